// Round 11
// baseline (287.745 us; speedup 1.0000x reference)
//
#include <hip/hip_runtime.h>
#include <cstdint>

typedef _Float16 f16;
typedef f16 f16x8 __attribute__((ext_vector_type(8)));
typedef f16 f16x4 __attribute__((ext_vector_type(4)));
typedef f16 f16x2 __attribute__((ext_vector_type(2)));
typedef float f32x4 __attribute__((ext_vector_type(4)));
typedef uint32_t u32x4 __attribute__((ext_vector_type(4)));

#define D_MODEL 1280
#define SEQ 2048
#define BATCH 4
#define HEADS 8
#define HDIM 160
#define MTOT (BATCH*SEQ)          // 8192
#define NQKV (3*D_MODEL)          // 3840

__device__ __forceinline__ void gload_lds16(const f16* g, f16* l) {
  __builtin_amdgcn_global_load_lds(
      (const __attribute__((address_space(1))) unsigned int*)g,
      (__attribute__((address_space(3))) unsigned int*)l,
      16, 0, 0);
}

#define BARX() { asm volatile("" ::: "memory"); __builtin_amdgcn_s_barrier(); asm volatile("" ::: "memory"); }
#define VMW(N) { asm volatile("s_waitcnt vmcnt(" #N ")" ::: "memory"); }

// ---------------- prep kernels ----------------

__global__ void convert_f32_to_f16(const float* __restrict__ in, f16* __restrict__ out, int n4) {
  int i = blockIdx.x * 256 + threadIdx.x;
  if (i < n4) {
    float4 v = ((const float4*)in)[i];
    f16x4 o = { (f16)v.x, (f16)v.y, (f16)v.z, (f16)v.w };
    ((f16x4*)out)[i] = o;
  }
}

// W_eff[o][i] = W[o][i] + sum_r up[o][r]*down[r][i]   (all 1280x1280, rank 4)
__global__ void build_weff(const float* __restrict__ W, const float* __restrict__ up,
                           const float* __restrict__ down, f16* __restrict__ out) {
  int idx = blockIdx.x * 256 + threadIdx.x;          // D*D/4 threads
  int o  = idx / (D_MODEL / 4);
  int i0 = (idx % (D_MODEL / 4)) * 4;
  float4 w = *(const float4*)&W[(size_t)o * D_MODEL + i0];
  float u0 = up[o*4+0], u1 = up[o*4+1], u2 = up[o*4+2], u3 = up[o*4+3];
  float vals[4] = { w.x, w.y, w.z, w.w };
  f16x4 r;
#pragma unroll
  for (int j = 0; j < 4; ++j) {
    int i = i0 + j;
    float acc = vals[j] + u0*down[i] + u1*down[D_MODEL + i]
                        + u2*down[2*D_MODEL + i] + u3*down[3*D_MODEL + i];
    r[j] = (f16)acc;
  }
  *(f16x4*)&out[(size_t)o * D_MODEL + i0] = r;
}

// V slice of qkv -> Vt [32 bh][160 d][2048 s], s sigma-permuted within each
// 32-block (sigma swaps 4-blocks [4-7]<->[8-11], [20-23]<->[24-27]; involution)
// to match the in-register P layout. Vectorized f16x4 both sides.
__global__ void transpose_v(const f16* __restrict__ qkv, f16* __restrict__ Vt) {
  __shared__ f16 t[32][36];
  int s0 = blockIdx.x * 32;
  int d0 = blockIdx.y * 32;
  int bh = blockIdx.z;
  int b = bh >> 3, h = bh & 7;
  int tid = threadIdx.x;
  {
    int i = tid >> 3, j4 = (tid & 7) * 4;
    *(f16x4*)&t[i][j4] =
        *(const f16x4*)&qkv[(size_t)(b*SEQ + s0 + i) * NQKV + 2*D_MODEL + h*HDIM + d0 + j4];
  }
  __syncthreads();
  {
    int dd = tid >> 3, s4 = (tid & 7) * 4;
    f16x4 v;
#pragma unroll
    for (int k = 0; k < 4; ++k) {
      int s = s4 + k;
      int sj = (((s>>2) ^ (s>>3)) & 1) ? (s ^ 12) : s;
      v[k] = t[sj][dd];
    }
    *(f16x4*)&Vt[(size_t)(bh*HDIM + d0 + dd) * SEQ + s0 + s4] = v;
  }
}

// ---------------- 256x256 deep-pipelined GEMM ----------------
// C[M][N] = A[M][K] * Bw[N][K]^T; K=1280. OUTF32: float out + bias; else f16.
// XCD-aware bijective swizzle: xcd = flat&7 owns bm in [xcd*4, xcd*4+4).
template<int OUTF32>
__global__ __launch_bounds__(512) void gemm256(const f16* __restrict__ A,
                                               const f16* __restrict__ Bw,
                                               void* __restrict__ Cp, int ldc,
                                               const float* __restrict__ bias) {
  const int K = D_MODEL, NT = D_MODEL/64;               // 20 K-tiles
  __shared__ alignas(16) f16 lds[7 * 8192];             // A: slots 0..2, B: slots 3..6
  f16* LB = lds + 3*8192;
  int tid = threadIdx.x;
  int wv = tid >> 6, l = tid & 63;
  int wm = wv >> 2, wn = wv & 3;
  int lr = l & 15, lg = l >> 4;

  int flat = blockIdx.y * gridDim.x + blockIdx.x;
  int bnn = gridDim.x;
  int xcd = flat & 7, idx = flat >> 3;
  int bm = xcd * 4 + idx / bnn;
  int bn = idx % bnn;

  int row0 = tid >> 3;
  int csw  = ((tid & 7) ^ (row0 & 7)) * 8;
  const f16* Asrc[2]; const f16* Bsrc[2];
#pragma unroll
  for (int h = 0; h < 2; ++h) {
    Asrc[h] = A  + (size_t)(bm*256 + h*128 + row0) * K + csw;
    Bsrc[h] = Bw + (size_t)(bn*256 + h*128 + row0) * K + csw;
  }
  int ldsoff = wv * 512;

  int xsl0 = ((lg)     ^ (lr & 7)) * 8;
  int xsl1 = ((4 + lg) ^ (lr & 7)) * 8;

  f32x4 acc[8][4] = {};

#define STAGE_A(h, slot, kt) { const f16* s_ = Asrc[h] + (kt)*64; f16* d_ = lds + (slot)*8192 + ldsoff; \
    gload_lds16(s_, d_); gload_lds16(s_ + (size_t)64*K, d_ + 4096); }
#define STAGE_B(h, slot, kt) { const f16* s_ = Bsrc[h] + (kt)*64; f16* d_ = LB + (slot)*8192 + ldsoff; \
    gload_lds16(s_, d_); gload_lds16(s_ + (size_t)64*K, d_ + 4096); }

  STAGE_A(0, 0, 0); STAGE_A(1, 1, 0);
  STAGE_B(0, 0, 0); STAGE_B(1, 1, 0);
  STAGE_B(0, 2, 1);
  VMW(2); BARX();

  for (int t = 0; t < NT; ++t) {
    int sA0 = (2*t) % 3, sA1 = (2*t+1) % 3, sA2 = (2*t+2) % 3;
    int sB0 = (2*t) & 3, sB1 = (2*t+1) & 3, sB3 = (2*t+3) & 3;
    int tc1 = (t+1 < NT) ? t+1 : NT-1;
    int tc2 = (t+2 < NT) ? t+2 : NT-1;

#define PHASE(ah, bh, sA, sB, STG, VMOPT) { \
    f16x8 af[4][2], bf[2][2]; \
    _Pragma("unroll") \
    for (int j = 0; j < 4; ++j) { \
      int base = (sA)*8192 + (wm*64 + j*16 + lr)*64; \
      af[j][0] = *(const f16x8*)&lds[base + xsl0]; \
      af[j][1] = *(const f16x8*)&lds[base + xsl1]; \
    } \
    _Pragma("unroll") \
    for (int i = 0; i < 2; ++i) { \
      int base = (sB)*8192 + (wn*32 + i*16 + lr)*64; \
      bf[i][0] = *(const f16x8*)&LB[base + xsl0]; \
      bf[i][1] = *(const f16x8*)&LB[base + xsl1]; \
    } \
    STG; \
    BARX(); \
    __builtin_amdgcn_s_setprio(1); \
    _Pragma("unroll") \
    for (int j = 0; j < 4; ++j) \
      _Pragma("unroll") \
      for (int i = 0; i < 2; ++i) { \
        acc[(ah)*4+j][(bh)*2+i] = __builtin_amdgcn_mfma_f32_16x16x32_f16(af[j][0], bf[i][0], acc[(ah)*4+j][(bh)*2+i], 0, 0, 0); \
        acc[(ah)*4+j][(bh)*2+i] = __builtin_amdgcn_mfma_f32_16x16x32_f16(af[j][1], bf[i][1], acc[(ah)*4+j][(bh)*2+i], 0, 0, 0); \
      } \
    __builtin_amdgcn_s_setprio(0); \
    VMOPT; \
    BARX(); }

    PHASE(0, 0, sA0, sB0, STAGE_B(1, sB3, tc1), VMW(2))
    PHASE(1, 0, sA1, sB0, STAGE_A(0, sA2, tc1), )
    PHASE(0, 1, sA0, sB1, STAGE_B(0, sB0, tc2), )
    PHASE(1, 1, sA1, sB1, STAGE_A(1, sA0, tc1), VMW(4))
#undef PHASE
  }

#pragma unroll
  for (int mf = 0; mf < 8; ++mf) {
    int r0 = bm*256 + (mf>>2)*128 + wm*64 + (mf&3)*16 + lg*4;
#pragma unroll
    for (int nf = 0; nf < 4; ++nf) {
      int c = bn*256 + (nf>>1)*128 + wn*32 + (nf&1)*16 + lr;
      if constexpr (OUTF32) {
        float bb = bias[c];
#pragma unroll
        for (int rg = 0; rg < 4; ++rg)
          ((float*)Cp)[(size_t)(r0 + rg) * ldc + c] = acc[mf][nf][rg] + bb;
      } else {
#pragma unroll
        for (int rg = 0; rg < 4; ++rg)
          ((f16*)Cp)[(size_t)(r0 + rg) * ldc + c] = (f16)acc[mf][nf][rg];
      }
    }
  }
#undef STAGE_A
#undef STAGE_B
}

// ---------------- flash attention v6 ----------------
// v5 + counted-vmcnt pipeline with double-buffered K:
//   QK[kt](Kcur) | b0 | issue K[kt+2]->Kcur | softmax/repack | vmcnt(6) b1 |
//   PV(Vl) | b2 | issue V[kt+1]->Vl
// Queue ledger (per wave, FIFO): at vmcnt(6): [V[kt](5), K[kt+2](6)] or
// [K[kt+1](6), V[kt](5), K[kt+2](6)] -> retires through V[kt]. No vmcnt(0)
// drain in the loop. All waves issue all 6 K insts (tail inst duplicated,
// same data -> benign) so counts are wave-uniform. LDS 63488 B, 2 blk/CU.
__global__ __launch_bounds__(256, 2) void attn(const f16* __restrict__ qkv,
                                               const f16* __restrict__ Vt,
                                               f16* __restrict__ ctx) {
  __shared__ alignas(16) f16 Kl[2][64 * 168]; // 43008 B
  __shared__ alignas(16) f16 Vl[160 * 64];    // 20480 B
  int tid = threadIdx.x;
  int wv = tid >> 6, l = tid & 63;
  int lr = l & 15, lg = l >> 4;
  int flat = blockIdx.y * 16 + blockIdx.x;    // 512 blocks
  int xcd = flat & 7, idx = flat >> 3;        // idx 0..63
  int bh = xcd * 4 + (idx >> 4);              // 4 bh per XCD
  int qt = idx & 15;
  int b = bh >> 3, h = bh & 7;
  size_t qrow[2];
#pragma unroll
  for (int qg = 0; qg < 2; ++qg)
    qrow[qg] = (size_t)(b*SEQ + qt*128 + wv*32 + qg*16 + lr);

  // Q fragments, pre-scaled by hd^-0.5 * log2(e) (exp2 domain)
  const f16 qscale = (f16)0.114055069f;
  f16x8 qf[2][5];
#pragma unroll
  for (int qg = 0; qg < 2; ++qg)
#pragma unroll
    for (int dk = 0; dk < 5; ++dk) {
      f16x8 t = *(const f16x8*)&qkv[qrow[qg] * NQKV + h*HDIM + dk*32 + lg*8];
#pragma unroll
      for (int j = 0; j < 8; ++j) t[j] = t[j] * qscale;
      qf[qg][dk] = t;
    }
  VMW(0);   // retire Q loads so loop vmcnt counts are exact

  // K staging: 1344 chunks; 6 insts/wave (tail duplicated across waves).
  const char* Kg0 = (const char*)qkv + (size_t)(b*SEQ)*NQKV*2 + (size_t)D_MODEL*2 + (size_t)h*HDIM*2;
  uint32_t koff[6], kldo[6];
#pragma unroll
  for (int it = 0; it < 6; ++it) {
    int p = (it < 5) ? it*256 + tid : 1280 + (tid & 63);
    koff[it] = (uint32_t)(p/21) * (NQKV*2) + (uint32_t)(p%21) * 16;
    kldo[it] = (it < 5) ? (uint32_t)(it*256 + wv*64)*16 : 1280*16;
  }

  // V staging: 1280 chunks; content XOR-swizzled (phys slot sp holds logical sp^(row&7)).
  const char* Vg0 = (const char*)Vt + (size_t)bh*HDIM*SEQ*2;
  char* VlB = (char*)Vl;
  uint32_t voff[5];
  f16* vld[5];
#pragma unroll
  for (int it = 0; it < 5; ++it) {
    int c = it*256 + tid;
    int row = c >> 3, sp = c & 7;
    voff[it] = (uint32_t)row * (SEQ*2) + (uint32_t)((sp ^ (row & 7)) * 16);
    vld[it] = (f16*)(VlB + (it*256 + wv*64)*16);
  }
  uint32_t vro[2];
#pragma unroll
  for (int ks = 0; ks < 2; ++ks)
    vro[ks] = (uint32_t)lr*128 + (uint32_t)((((ks*4+lg) ^ (lr & 7)) * 16));

  f32x4 oacc[10][2] = {};
  float m[2] = {-1e30f, -1e30f}, lsum[2] = {0.f, 0.f};

#define STAGE_K(kt, CUR) { const char* Ks_ = Kg0 + (size_t)(kt)*(64*NQKV*2); \
    _Pragma("unroll") \
    for (int it = 0; it < 6; ++it) \
      gload_lds16((const f16*)(Ks_ + koff[it]), (f16*)((char*)Kl[CUR] + kldo[it])); }
#define STAGE_V(kt) { const char* Vs_ = Vg0 + (size_t)(kt)*128; \
    _Pragma("unroll") \
    for (int it = 0; it < 5; ++it) \
      gload_lds16((const f16*)(Vs_ + voff[it]), vld[it]); }

  // prologue: K[0]->buf0 (6), V[0] (5), K[1]->buf1 (6); wait K[0] only.
  STAGE_K(0, 0);
  STAGE_V(0);
  STAGE_K(1, 1);
  VMW(11); BARX();

#define ITER(ktc, CUR) { \
    f32x4 sc[4][2] = {}; \
    __builtin_amdgcn_s_setprio(1); \
    _Pragma("unroll") \
    for (int kb = 0; kb < 4; ++kb) \
      _Pragma("unroll") \
      for (int dk = 0; dk < 5; ++dk) { \
        f16x8 a = *(const f16x8*)&Kl[CUR][(kb*16 + lr)*168 + dk*32 + lg*8]; \
        sc[kb][0] = __builtin_amdgcn_mfma_f32_16x16x32_f16(a, qf[0][dk], sc[kb][0], 0, 0, 0); \
        sc[kb][1] = __builtin_amdgcn_mfma_f32_16x16x32_f16(a, qf[1][dk], sc[kb][1], 0, 0, 0); \
      } \
    __builtin_amdgcn_s_setprio(0); \
    BARX();  /* b0: Kl[CUR] readers done */ \
    { int k2_ = (ktc)+2 < 32 ? (ktc)+2 : 31; STAGE_K(k2_, CUR); } \
    float smax[2]; \
    _Pragma("unroll") \
    for (int qg = 0; qg < 2; ++qg) { \
      float sm = -1e30f; \
      _Pragma("unroll") \
      for (int kb = 0; kb < 4; ++kb) \
        _Pragma("unroll") \
        for (int rg = 0; rg < 4; ++rg) sm = fmaxf(sm, sc[kb][qg][rg]); \
      sm = fmaxf(sm, __shfl_xor(sm, 16)); \
      sm = fmaxf(sm, __shfl_xor(sm, 32)); \
      smax[qg] = sm; \
    } \
    if (!__all(fmaxf(smax[0] - m[0], smax[1] - m[1]) <= 11.54f)) { \
      _Pragma("unroll") \
      for (int qg = 0; qg < 2; ++qg) { \
        float mn = fmaxf(m[qg], smax[qg]); \
        float alpha = exp2f(m[qg] - mn); \
        _Pragma("unroll") \
        for (int df = 0; df < 10; ++df) \
          _Pragma("unroll") \
          for (int rg = 0; rg < 4; ++rg) oacc[df][qg][rg] *= alpha; \
        lsum[qg] *= alpha; \
        m[qg] = mn; \
      } \
    } \
    f16x8 pb[2][2]; \
    _Pragma("unroll") \
    for (int qg = 0; qg < 2; ++qg) { \
      float ps[16]; \
      float psum = 0.f; \
      _Pragma("unroll") \
      for (int kb = 0; kb < 4; ++kb) \
        _Pragma("unroll") \
        for (int rg = 0; rg < 4; ++rg) { \
          float p = exp2f(sc[kb][qg][rg] - m[qg]); \
          ps[kb*4 + rg] = p; \
          psum += p; \
        } \
      psum += __shfl_xor(psum, 16); \
      psum += __shfl_xor(psum, 32); \
      lsum[qg] += psum; \
      uint32_t w0, w1, w2, w3, w4, w5, w6, w7; \
      asm("v_cvt_pkrtz_f16_f32 %0, %1, %2" : "=v"(w0) : "v"(ps[0]),  "v"(ps[1])); \
      asm("v_cvt_pkrtz_f16_f32 %0, %1, %2" : "=v"(w1) : "v"(ps[2]),  "v"(ps[3])); \
      asm("v_cvt_pkrtz_f16_f32 %0, %1, %2" : "=v"(w2) : "v"(ps[4]),  "v"(ps[5])); \
      asm("v_cvt_pkrtz_f16_f32 %0, %1, %2" : "=v"(w3) : "v"(ps[6]),  "v"(ps[7])); \
      asm("v_cvt_pkrtz_f16_f32 %0, %1, %2" : "=v"(w4) : "v"(ps[8]),  "v"(ps[9])); \
      asm("v_cvt_pkrtz_f16_f32 %0, %1, %2" : "=v"(w5) : "v"(ps[10]), "v"(ps[11])); \
      asm("v_cvt_pkrtz_f16_f32 %0, %1, %2" : "=v"(w6) : "v"(ps[12]), "v"(ps[13])); \
      asm("v_cvt_pkrtz_f16_f32 %0, %1, %2" : "=v"(w7) : "v"(ps[14]), "v"(ps[15])); \
      asm("v_permlane32_swap_b32 %0, %1" : "+v"(w0), "+v"(w2)); \
      asm("v_permlane32_swap_b32 %0, %1" : "+v"(w1), "+v"(w3)); \
      asm("v_permlane32_swap_b32 %0, %1" : "+v"(w4), "+v"(w6)); \
      asm("v_permlane32_swap_b32 %0, %1" : "+v"(w5), "+v"(w7)); \
      u32x4 c0 = { w0, w1, w2, w3 }; \
      u32x4 c1 = { w4, w5, w6, w7 }; \
      pb[qg][0] = __builtin_bit_cast(f16x8, c0); \
      pb[qg][1] = __builtin_bit_cast(f16x8, c1); \
    } \
    VMW(6); BARX();  /* b1: V[ktc] landed (retires through V; K[ktc+2] stays) */ \
    __builtin_amdgcn_s_setprio(1); \
    _Pragma("unroll") \
    for (int df = 0; df < 10; ++df) \
      _Pragma("unroll") \
      for (int ks = 0; ks < 2; ++ks) { \
        f16x8 a = *(const f16x8*)(VlB + vro[ks] + df*2048); \
        oacc[df][0] = __builtin_amdgcn_mfma_f32_16x16x32_f16(a, pb[0][ks], oacc[df][0], 0, 0, 0); \
        oacc[df][1] = __builtin_amdgcn_mfma_f32_16x16x32_f16(a, pb[1][ks], oacc[df][1], 0, 0, 0); \
      } \
    __builtin_amdgcn_s_setprio(0); \
    BARX();  /* b2: Vl readers done */ \
    { int k1_ = (ktc)+1 < 32 ? (ktc)+1 : 31; STAGE_V(k1_); } \
  }

  for (int kt = 0; kt < 32; kt += 2) {
    ITER(kt, 0)
    ITER(kt + 1, 1)
  }
#undef ITER
#undef STAGE_K
#undef STAGE_V

  VMW(0);   // drain clamped tail stages before exit

#pragma unroll
  for (int qg = 0; qg < 2; ++qg) {
    float inv = 1.f / lsum[qg];
#pragma unroll
    for (int df = 0; df < 10; ++df)
#pragma unroll
      for (int pr = 0; pr < 2; ++pr) {
        f16x2 pv = { (f16)(oacc[df][qg][pr*2+0] * inv), (f16)(oacc[df][qg][pr*2+1] * inv) };
        *(f16x2*)&ctx[qrow[qg] * D_MODEL + h*HDIM + df*16 + lg*4 + pr*2] = pv;
      }
  }
}

// ---------------- launcher ----------------

extern "C" void kernel_launch(void* const* d_in, const int* in_sizes, int n_in,
                              void* d_out, int out_size, void* d_ws, size_t ws_size,
                              hipStream_t stream) {
  const float* x   = (const float*)d_in[0];
  const float* Wq  = (const float*)d_in[1];
  const float* Wk  = (const float*)d_in[2];
  const float* Wv  = (const float*)d_in[3];
  const float* Wo  = (const float*)d_in[4];
  const float* bo  = (const float*)d_in[5];
  const float* q_down = (const float*)d_in[6];
  const float* q_up   = (const float*)d_in[7];
  const float* k_down = (const float*)d_in[8];
  const float* k_up   = (const float*)d_in[9];
  const float* v_down = (const float*)d_in[10];
  const float* v_up   = (const float*)d_in[11];
  const float* o_down = (const float*)d_in[12];
  const float* o_up   = (const float*)d_in[13];
  float* out = (float*)d_out;

  char* ws = (char*)d_ws;
  f16* xh    = (f16*)ws;                                  // 8192x1280 (reused as ctx)
  f16* Wqkv  = (f16*)(ws + 20971520);                     // 3840x1280
  f16* WoE   = (f16*)(ws + 20971520 + 9830400);           // 1280x1280
  f16* qkv   = (f16*)(ws + 20971520 + 9830400 + 3276800); // 8192x3840
  f16* Vt    = (f16*)(ws + 20971520 + 9830400 + 3276800 + 62914560); // 32x160x2048
  f16* ctx   = xh;

  convert_f32_to_f16<<<(MTOT*D_MODEL/4 + 255)/256, 256, 0, stream>>>(x, xh, MTOT*D_MODEL/4);
  build_weff<<<D_MODEL*D_MODEL/4/256, 256, 0, stream>>>(Wq, q_up, q_down, Wqkv);
  build_weff<<<D_MODEL*D_MODEL/4/256, 256, 0, stream>>>(Wk, k_up, k_down, Wqkv + (size_t)D_MODEL*D_MODEL);
  build_weff<<<D_MODEL*D_MODEL/4/256, 256, 0, stream>>>(Wv, v_up, v_down, Wqkv + (size_t)2*D_MODEL*D_MODEL);
  build_weff<<<D_MODEL*D_MODEL/4/256, 256, 0, stream>>>(Wo, o_up, o_down, WoE);

  gemm256<0><<<dim3(NQKV/256, MTOT/256), 512, 0, stream>>>(xh, Wqkv, qkv, NQKV, nullptr);
  transpose_v<<<dim3(SEQ/32, HDIM/32, BATCH*HEADS), 256, 0, stream>>>(qkv, Vt);
  attn<<<dim3(SEQ/128, BATCH*HEADS), 256, 0, stream>>>(qkv, Vt, ctx);
  gemm256<1><<<dim3(D_MODEL/256, MTOT/256), 512, 0, stream>>>(ctx, WoE, out, D_MODEL, bo);
  (void)in_sizes; (void)n_in; (void)out_size; (void)ws_size;
}

// Round 12
// 272.616 us; speedup vs baseline: 1.0555x; 1.0555x over previous
//
#include <hip/hip_runtime.h>
#include <cstdint>

typedef _Float16 f16;
typedef f16 f16x8 __attribute__((ext_vector_type(8)));
typedef f16 f16x4 __attribute__((ext_vector_type(4)));
typedef f16 f16x2 __attribute__((ext_vector_type(2)));
typedef float f32x4 __attribute__((ext_vector_type(4)));
typedef uint32_t u32x4 __attribute__((ext_vector_type(4)));

#define D_MODEL 1280
#define SEQ 2048
#define BATCH 4
#define HEADS 8
#define HDIM 160
#define MTOT (BATCH*SEQ)          // 8192
#define NQKV (3*D_MODEL)          // 3840

__device__ __forceinline__ void gload_lds16(const f16* g, f16* l) {
  __builtin_amdgcn_global_load_lds(
      (const __attribute__((address_space(1))) unsigned int*)g,
      (__attribute__((address_space(3))) unsigned int*)l,
      16, 0, 0);
}

#define BARX() { asm volatile("" ::: "memory"); __builtin_amdgcn_s_barrier(); asm volatile("" ::: "memory"); }
#define VMW(N) { asm volatile("s_waitcnt vmcnt(" #N ")" ::: "memory"); }

// ---------------- prep kernels ----------------

__global__ void convert_f32_to_f16(const float* __restrict__ in, f16* __restrict__ out, int n4) {
  int i = blockIdx.x * 256 + threadIdx.x;
  if (i < n4) {
    float4 v = ((const float4*)in)[i];
    f16x4 o = { (f16)v.x, (f16)v.y, (f16)v.z, (f16)v.w };
    ((f16x4*)out)[i] = o;
  }
}

// W_eff[o][i] = W[o][i] + sum_r up[o][r]*down[r][i]; 4 weight sets in one launch
__global__ void build_weff4(const float* __restrict__ W0, const float* __restrict__ W1,
                            const float* __restrict__ W2, const float* __restrict__ W3,
                            const float* __restrict__ u0, const float* __restrict__ u1,
                            const float* __restrict__ u2, const float* __restrict__ u3,
                            const float* __restrict__ n0, const float* __restrict__ n1,
                            const float* __restrict__ n2, const float* __restrict__ n3,
                            f16* __restrict__ o0, f16* __restrict__ o1,
                            f16* __restrict__ o2, f16* __restrict__ o3) {
  int which = blockIdx.y;
  const float* W    = which==0 ? W0 : which==1 ? W1 : which==2 ? W2 : W3;
  const float* up   = which==0 ? u0 : which==1 ? u1 : which==2 ? u2 : u3;
  const float* down = which==0 ? n0 : which==1 ? n1 : which==2 ? n2 : n3;
  f16* out          = which==0 ? o0 : which==1 ? o1 : which==2 ? o2 : o3;
  int idx = blockIdx.x * 256 + threadIdx.x;          // D*D/4 threads
  int o  = idx / (D_MODEL / 4);
  int i0 = (idx % (D_MODEL / 4)) * 4;
  float4 w = *(const float4*)&W[(size_t)o * D_MODEL + i0];
  float p0 = up[o*4+0], p1 = up[o*4+1], p2 = up[o*4+2], p3 = up[o*4+3];
  float vals[4] = { w.x, w.y, w.z, w.w };
  f16x4 r;
#pragma unroll
  for (int j = 0; j < 4; ++j) {
    int i = i0 + j;
    float acc = vals[j] + p0*down[i] + p1*down[D_MODEL + i]
                        + p2*down[2*D_MODEL + i] + p3*down[3*D_MODEL + i];
    r[j] = (f16)acc;
  }
  *(f16x4*)&out[(size_t)o * D_MODEL + i0] = r;
}

// V slice of qkv -> Vt [32 bh][160 d][2048 s], s sigma-permuted within each
// 32-block (sigma swaps 4-blocks [4-7]<->[8-11], [20-23]<->[24-27]; involution)
// to match the in-register P layout. Vectorized f16x4 both sides.
__global__ void transpose_v(const f16* __restrict__ qkv, f16* __restrict__ Vt) {
  __shared__ f16 t[32][36];
  int s0 = blockIdx.x * 32;
  int d0 = blockIdx.y * 32;
  int bh = blockIdx.z;
  int b = bh >> 3, h = bh & 7;
  int tid = threadIdx.x;
  {
    int i = tid >> 3, j4 = (tid & 7) * 4;
    *(f16x4*)&t[i][j4] =
        *(const f16x4*)&qkv[(size_t)(b*SEQ + s0 + i) * NQKV + 2*D_MODEL + h*HDIM + d0 + j4];
  }
  __syncthreads();
  {
    int dd = tid >> 3, s4 = (tid & 7) * 4;
    f16x4 v;
#pragma unroll
    for (int k = 0; k < 4; ++k) {
      int s = s4 + k;
      int sj = (((s>>2) ^ (s>>3)) & 1) ? (s ^ 12) : s;
      v[k] = t[sj][dd];
    }
    *(f16x4*)&Vt[(size_t)(bh*HDIM + d0 + dd) * SEQ + s0 + s4] = v;
  }
}

// ---------------- 256x256 deep-pipelined GEMM ----------------
// C[M][N] = A[M][K] * Bw[N][K]^T; K=1280. OUTF32: float out + bias; else f16.
// XCD-aware bijective swizzle: xcd = flat&7 owns bm in [xcd*4, xcd*4+4).
template<int OUTF32>
__global__ __launch_bounds__(512) void gemm256(const f16* __restrict__ A,
                                               const f16* __restrict__ Bw,
                                               void* __restrict__ Cp, int ldc,
                                               const float* __restrict__ bias) {
  const int K = D_MODEL, NT = D_MODEL/64;               // 20 K-tiles
  __shared__ alignas(16) f16 lds[7 * 8192];             // A: slots 0..2, B: slots 3..6
  f16* LB = lds + 3*8192;
  int tid = threadIdx.x;
  int wv = tid >> 6, l = tid & 63;
  int wm = wv >> 2, wn = wv & 3;
  int lr = l & 15, lg = l >> 4;

  int flat = blockIdx.y * gridDim.x + blockIdx.x;
  int bnn = gridDim.x;
  int xcd = flat & 7, idx = flat >> 3;
  int bm = xcd * 4 + idx / bnn;
  int bn = idx % bnn;

  int row0 = tid >> 3;
  int csw  = ((tid & 7) ^ (row0 & 7)) * 8;
  const f16* Asrc[2]; const f16* Bsrc[2];
#pragma unroll
  for (int h = 0; h < 2; ++h) {
    Asrc[h] = A  + (size_t)(bm*256 + h*128 + row0) * K + csw;
    Bsrc[h] = Bw + (size_t)(bn*256 + h*128 + row0) * K + csw;
  }
  int ldsoff = wv * 512;

  int xsl0 = ((lg)     ^ (lr & 7)) * 8;
  int xsl1 = ((4 + lg) ^ (lr & 7)) * 8;

  f32x4 acc[8][4] = {};

#define STAGE_A(h, slot, kt) { const f16* s_ = Asrc[h] + (kt)*64; f16* d_ = lds + (slot)*8192 + ldsoff; \
    gload_lds16(s_, d_); gload_lds16(s_ + (size_t)64*K, d_ + 4096); }
#define STAGE_B(h, slot, kt) { const f16* s_ = Bsrc[h] + (kt)*64; f16* d_ = LB + (slot)*8192 + ldsoff; \
    gload_lds16(s_, d_); gload_lds16(s_ + (size_t)64*K, d_ + 4096); }

  STAGE_A(0, 0, 0); STAGE_A(1, 1, 0);
  STAGE_B(0, 0, 0); STAGE_B(1, 1, 0);
  STAGE_B(0, 2, 1);
  VMW(2); BARX();

  for (int t = 0; t < NT; ++t) {
    int sA0 = (2*t) % 3, sA1 = (2*t+1) % 3, sA2 = (2*t+2) % 3;
    int sB0 = (2*t) & 3, sB1 = (2*t+1) & 3, sB3 = (2*t+3) & 3;
    int tc1 = (t+1 < NT) ? t+1 : NT-1;
    int tc2 = (t+2 < NT) ? t+2 : NT-1;

#define PHASE(ah, bh, sA, sB, STG, VMOPT) { \
    f16x8 af[4][2], bf[2][2]; \
    _Pragma("unroll") \
    for (int j = 0; j < 4; ++j) { \
      int base = (sA)*8192 + (wm*64 + j*16 + lr)*64; \
      af[j][0] = *(const f16x8*)&lds[base + xsl0]; \
      af[j][1] = *(const f16x8*)&lds[base + xsl1]; \
    } \
    _Pragma("unroll") \
    for (int i = 0; i < 2; ++i) { \
      int base = (sB)*8192 + (wn*32 + i*16 + lr)*64; \
      bf[i][0] = *(const f16x8*)&LB[base + xsl0]; \
      bf[i][1] = *(const f16x8*)&LB[base + xsl1]; \
    } \
    STG; \
    BARX(); \
    __builtin_amdgcn_s_setprio(1); \
    _Pragma("unroll") \
    for (int j = 0; j < 4; ++j) \
      _Pragma("unroll") \
      for (int i = 0; i < 2; ++i) { \
        acc[(ah)*4+j][(bh)*2+i] = __builtin_amdgcn_mfma_f32_16x16x32_f16(af[j][0], bf[i][0], acc[(ah)*4+j][(bh)*2+i], 0, 0, 0); \
        acc[(ah)*4+j][(bh)*2+i] = __builtin_amdgcn_mfma_f32_16x16x32_f16(af[j][1], bf[i][1], acc[(ah)*4+j][(bh)*2+i], 0, 0, 0); \
      } \
    __builtin_amdgcn_s_setprio(0); \
    VMOPT; \
    BARX(); }

    PHASE(0, 0, sA0, sB0, STAGE_B(1, sB3, tc1), VMW(2))
    PHASE(1, 0, sA1, sB0, STAGE_A(0, sA2, tc1), )
    PHASE(0, 1, sA0, sB1, STAGE_B(0, sB0, tc2), )
    PHASE(1, 1, sA1, sB1, STAGE_A(1, sA0, tc1), VMW(4))
#undef PHASE
  }

#pragma unroll
  for (int mf = 0; mf < 8; ++mf) {
    int r0 = bm*256 + (mf>>2)*128 + wm*64 + (mf&3)*16 + lg*4;
#pragma unroll
    for (int nf = 0; nf < 4; ++nf) {
      int c = bn*256 + (nf>>1)*128 + wn*32 + (nf&1)*16 + lr;
      if constexpr (OUTF32) {
        float bb = bias[c];
#pragma unroll
        for (int rg = 0; rg < 4; ++rg)
          ((float*)Cp)[(size_t)(r0 + rg) * ldc + c] = acc[mf][nf][rg] + bb;
      } else {
#pragma unroll
        for (int rg = 0; rg < 4; ++rg)
          ((f16*)Cp)[(size_t)(r0 + rg) * ldc + c] = (f16)acc[mf][nf][rg];
      }
    }
  }
#undef STAGE_A
#undef STAGE_B
}

// ---------------- flash attention v5b ----------------
// R10 v5 structure (proven 123.5 us) + two chain-latency shaves:
//  - smax tree-reduce (depth 4 instead of 15 serial fmax)
//  - lsum cross-lane reduction deferred to epilogue (alpha is row-uniform
//    across lg groups, so per-lane partials stay consistently scaled);
//    drops 4 shfl_xor (LDS crossbar ops) from every iteration.
__global__ __launch_bounds__(256, 2) void attn(const f16* __restrict__ qkv,
                                               const f16* __restrict__ Vt,
                                               f16* __restrict__ ctx) {
  __shared__ alignas(16) f16 Kl[64 * 168];    // 21504 B
  __shared__ alignas(16) f16 Vl[160 * 64];    // 20480 B
  int tid = threadIdx.x;
  int wv = tid >> 6, l = tid & 63;
  int lr = l & 15, lg = l >> 4;
  int flat = blockIdx.y * 16 + blockIdx.x;    // 512 blocks
  int xcd = flat & 7, idx = flat >> 3;        // idx 0..63
  int bh = xcd * 4 + (idx >> 4);              // 4 bh per XCD
  int qt = idx & 15;
  int b = bh >> 3, h = bh & 7;
  size_t qrow[2];
#pragma unroll
  for (int qg = 0; qg < 2; ++qg)
    qrow[qg] = (size_t)(b*SEQ + qt*128 + wv*32 + qg*16 + lr);

  // Q fragments, pre-scaled by hd^-0.5 * log2(e) (exp2 domain)
  const f16 qscale = (f16)0.114055069f;
  f16x8 qf[2][5];
#pragma unroll
  for (int qg = 0; qg < 2; ++qg)
#pragma unroll
    for (int dk = 0; dk < 5; ++dk) {
      f16x8 t = *(const f16x8*)&qkv[qrow[qg] * NQKV + h*HDIM + dk*32 + lg*8];
#pragma unroll
      for (int j = 0; j < 8; ++j) t[j] = t[j] * qscale;
      qf[qg][dk] = t;
    }

  // K staging: 1344 chunks (5x256 + 64 on wave 0); slot 20 = pad (garbage ok).
  const char* Kg0 = (const char*)qkv + (size_t)(b*SEQ)*NQKV*2 + (size_t)D_MODEL*2 + (size_t)h*HDIM*2;
  char* KlB = (char*)Kl;
  uint32_t koff[6];
  f16* kld[6];
#pragma unroll
  for (int it = 0; it < 6; ++it) {
    int p = (it < 5) ? it*256 + tid : 1280 + (tid & 63);
    koff[it] = (uint32_t)(p/21) * (NQKV*2) + (uint32_t)(p%21) * 16;
    kld[it] = (f16*)(KlB + ((it < 5) ? (it*256 + wv*64)*16 : 1280*16));
  }

  // V staging: 1280 chunks; content XOR-swizzled (phys slot sp holds logical sp^(row&7)).
  const char* Vg0 = (const char*)Vt + (size_t)bh*HDIM*SEQ*2;
  char* VlB = (char*)Vl;
  uint32_t voff[5];
  f16* vld[5];
#pragma unroll
  for (int it = 0; it < 5; ++it) {
    int c = it*256 + tid;
    int row = c >> 3, sp = c & 7;
    voff[it] = (uint32_t)row * (SEQ*2) + (uint32_t)((sp ^ (row & 7)) * 16);
    vld[it] = (f16*)(VlB + (it*256 + wv*64)*16);
  }
  uint32_t vro[2];
#pragma unroll
  for (int ks = 0; ks < 2; ++ks)
    vro[ks] = (uint32_t)lr*128 + (uint32_t)((((ks*4+lg) ^ (lr & 7)) * 16));

  f32x4 oacc[10][2] = {};
  float m[2] = {-1e30f, -1e30f}, lsum[2] = {0.f, 0.f};

  for (int kt = 0; kt < 32; ++kt) {
    const char* Ksrc = Kg0 + (size_t)kt * (64*NQKV*2);
    const char* Vsrc = Vg0 + (size_t)kt * 128;
#pragma unroll
    for (int it = 0; it < 5; ++it) {
      gload_lds16((const f16*)(Ksrc + koff[it]), kld[it]);
      gload_lds16((const f16*)(Vsrc + voff[it]), vld[it]);
    }
    if (wv == 0)
      gload_lds16((const f16*)(Ksrc + koff[5]), kld[5]);
    __syncthreads();

    // S^T[kr][q], both q-groups share each K fragment
    f32x4 sc[4][2] = {};
    __builtin_amdgcn_s_setprio(1);
#pragma unroll
    for (int kb = 0; kb < 4; ++kb)
#pragma unroll
      for (int dk = 0; dk < 5; ++dk) {
        f16x8 a = *(const f16x8*)&Kl[(kb*16 + lr)*168 + dk*32 + lg*8];
        sc[kb][0] = __builtin_amdgcn_mfma_f32_16x16x32_f16(a, qf[0][dk], sc[kb][0], 0, 0, 0);
        sc[kb][1] = __builtin_amdgcn_mfma_f32_16x16x32_f16(a, qf[1][dk], sc[kb][1], 0, 0, 0);
      }
    __builtin_amdgcn_s_setprio(0);

    // row maxes via pairwise tree (depth 4), then cross-lane reduce
    float smax[2];
#pragma unroll
    for (int qg = 0; qg < 2; ++qg) {
      float a0 = fmaxf(fmaxf(sc[0][qg][0], sc[0][qg][1]), fmaxf(sc[0][qg][2], sc[0][qg][3]));
      float a1 = fmaxf(fmaxf(sc[1][qg][0], sc[1][qg][1]), fmaxf(sc[1][qg][2], sc[1][qg][3]));
      float a2 = fmaxf(fmaxf(sc[2][qg][0], sc[2][qg][1]), fmaxf(sc[2][qg][2], sc[2][qg][3]));
      float a3 = fmaxf(fmaxf(sc[3][qg][0], sc[3][qg][1]), fmaxf(sc[3][qg][2], sc[3][qg][3]));
      float sm = fmaxf(fmaxf(a0, a1), fmaxf(a2, a3));
      sm = fmaxf(sm, __shfl_xor(sm, 16));
      sm = fmaxf(sm, __shfl_xor(sm, 32));
      smax[qg] = sm;
    }
    if (!__all(fmaxf(smax[0] - m[0], smax[1] - m[1]) <= 11.54f)) {
#pragma unroll
      for (int qg = 0; qg < 2; ++qg) {
        float mn = fmaxf(m[qg], smax[qg]);
        float alpha = exp2f(m[qg] - mn);
#pragma unroll
        for (int df = 0; df < 10; ++df)
#pragma unroll
          for (int rg = 0; rg < 4; ++rg) oacc[df][qg][rg] *= alpha;
        lsum[qg] *= alpha;
        m[qg] = mn;
      }
    }

    // per-qg: exp2 -> per-lane partial sum -> in-register repack
    f16x8 pb[2][2];
#pragma unroll
    for (int qg = 0; qg < 2; ++qg) {
      float ps[16];
#pragma unroll
      for (int kb = 0; kb < 4; ++kb)
#pragma unroll
        for (int rg = 0; rg < 4; ++rg)
          ps[kb*4 + rg] = exp2f(sc[kb][qg][rg] - m[qg]);
      float s0 = (ps[0] + ps[1]) + (ps[2] + ps[3]);
      float s1 = (ps[4] + ps[5]) + (ps[6] + ps[7]);
      float s2 = (ps[8] + ps[9]) + (ps[10] + ps[11]);
      float s3 = (ps[12] + ps[13]) + (ps[14] + ps[15]);
      lsum[qg] += (s0 + s1) + (s2 + s3);   // cross-lane reduce deferred

      uint32_t w0, w1, w2, w3, w4, w5, w6, w7;
      asm("v_cvt_pkrtz_f16_f32 %0, %1, %2" : "=v"(w0) : "v"(ps[0]),  "v"(ps[1]));
      asm("v_cvt_pkrtz_f16_f32 %0, %1, %2" : "=v"(w1) : "v"(ps[2]),  "v"(ps[3]));
      asm("v_cvt_pkrtz_f16_f32 %0, %1, %2" : "=v"(w2) : "v"(ps[4]),  "v"(ps[5]));
      asm("v_cvt_pkrtz_f16_f32 %0, %1, %2" : "=v"(w3) : "v"(ps[6]),  "v"(ps[7]));
      asm("v_cvt_pkrtz_f16_f32 %0, %1, %2" : "=v"(w4) : "v"(ps[8]),  "v"(ps[9]));
      asm("v_cvt_pkrtz_f16_f32 %0, %1, %2" : "=v"(w5) : "v"(ps[10]), "v"(ps[11]));
      asm("v_cvt_pkrtz_f16_f32 %0, %1, %2" : "=v"(w6) : "v"(ps[12]), "v"(ps[13]));
      asm("v_cvt_pkrtz_f16_f32 %0, %1, %2" : "=v"(w7) : "v"(ps[14]), "v"(ps[15]));
      asm("v_permlane32_swap_b32 %0, %1" : "+v"(w0), "+v"(w2));
      asm("v_permlane32_swap_b32 %0, %1" : "+v"(w1), "+v"(w3));
      asm("v_permlane32_swap_b32 %0, %1" : "+v"(w4), "+v"(w6));
      asm("v_permlane32_swap_b32 %0, %1" : "+v"(w5), "+v"(w7));
      u32x4 c0 = { w0, w1, w2, w3 };
      u32x4 c1 = { w4, w5, w6, w7 };
      pb[qg][0] = __builtin_bit_cast(f16x8, c0);
      pb[qg][1] = __builtin_bit_cast(f16x8, c1);
    }

    // PV: each V fragment feeds both q-groups
    __builtin_amdgcn_s_setprio(1);
#pragma unroll
    for (int df = 0; df < 10; ++df)
#pragma unroll
      for (int ks = 0; ks < 2; ++ks) {
        f16x8 a = *(const f16x8*)(VlB + vro[ks] + df*2048);
        oacc[df][0] = __builtin_amdgcn_mfma_f32_16x16x32_f16(a, pb[0][ks], oacc[df][0], 0, 0, 0);
        oacc[df][1] = __builtin_amdgcn_mfma_f32_16x16x32_f16(a, pb[1][ks], oacc[df][1], 0, 0, 0);
      }
    __builtin_amdgcn_s_setprio(0);
    __syncthreads();
  }

  // deferred cross-lane lsum reduction (partials consistently scaled by alpha)
#pragma unroll
  for (int qg = 0; qg < 2; ++qg) {
    lsum[qg] += __shfl_xor(lsum[qg], 16);
    lsum[qg] += __shfl_xor(lsum[qg], 32);
  }

#pragma unroll
  for (int qg = 0; qg < 2; ++qg) {
    float inv = 1.f / lsum[qg];
#pragma unroll
    for (int df = 0; df < 10; ++df)
#pragma unroll
      for (int pr = 0; pr < 2; ++pr) {
        f16x2 pv = { (f16)(oacc[df][qg][pr*2+0] * inv), (f16)(oacc[df][qg][pr*2+1] * inv) };
        *(f16x2*)&ctx[qrow[qg] * D_MODEL + h*HDIM + df*16 + lg*4 + pr*2] = pv;
      }
  }
}

// ---------------- launcher ----------------

extern "C" void kernel_launch(void* const* d_in, const int* in_sizes, int n_in,
                              void* d_out, int out_size, void* d_ws, size_t ws_size,
                              hipStream_t stream) {
  const float* x   = (const float*)d_in[0];
  const float* Wq  = (const float*)d_in[1];
  const float* Wk  = (const float*)d_in[2];
  const float* Wv  = (const float*)d_in[3];
  const float* Wo  = (const float*)d_in[4];
  const float* bo  = (const float*)d_in[5];
  const float* q_down = (const float*)d_in[6];
  const float* q_up   = (const float*)d_in[7];
  const float* k_down = (const float*)d_in[8];
  const float* k_up   = (const float*)d_in[9];
  const float* v_down = (const float*)d_in[10];
  const float* v_up   = (const float*)d_in[11];
  const float* o_down = (const float*)d_in[12];
  const float* o_up   = (const float*)d_in[13];
  float* out = (float*)d_out;

  char* ws = (char*)d_ws;
  f16* xh    = (f16*)ws;                                  // 8192x1280 (reused as ctx)
  f16* Wqkv  = (f16*)(ws + 20971520);                     // 3840x1280
  f16* WoE   = (f16*)(ws + 20971520 + 9830400);           // 1280x1280
  f16* qkv   = (f16*)(ws + 20971520 + 9830400 + 3276800); // 8192x3840
  f16* Vt    = (f16*)(ws + 20971520 + 9830400 + 3276800 + 62914560); // 32x160x2048
  f16* ctx   = xh;

  convert_f32_to_f16<<<(MTOT*D_MODEL/4 + 255)/256, 256, 0, stream>>>(x, xh, MTOT*D_MODEL/4);
  build_weff4<<<dim3(D_MODEL*D_MODEL/4/256, 4), 256, 0, stream>>>(
      Wq, Wk, Wv, Wo, q_up, k_up, v_up, o_up, q_down, k_down, v_down, o_down,
      Wqkv, Wqkv + (size_t)D_MODEL*D_MODEL, Wqkv + (size_t)2*D_MODEL*D_MODEL, WoE);

  gemm256<0><<<dim3(NQKV/256, MTOT/256), 512, 0, stream>>>(xh, Wqkv, qkv, NQKV, nullptr);
  transpose_v<<<dim3(SEQ/32, HDIM/32, BATCH*HEADS), 256, 0, stream>>>(qkv, Vt);
  attn<<<dim3(SEQ/128, BATCH*HEADS), 256, 0, stream>>>(qkv, Vt, ctx);
  gemm256<1><<<dim3(D_MODEL/256, MTOT/256), 512, 0, stream>>>(ctx, WoE, out, D_MODEL, bo);
  (void)in_sizes; (void)n_in; (void)out_size; (void)ws_size;
}

// Round 13
// 267.524 us; speedup vs baseline: 1.0756x; 1.0190x over previous
//
#include <hip/hip_runtime.h>
#include <cstdint>

typedef _Float16 f16;
typedef f16 f16x8 __attribute__((ext_vector_type(8)));
typedef f16 f16x4 __attribute__((ext_vector_type(4)));
typedef f16 f16x2 __attribute__((ext_vector_type(2)));
typedef float f32x4 __attribute__((ext_vector_type(4)));
typedef uint32_t u32x4 __attribute__((ext_vector_type(4)));

#define D_MODEL 1280
#define SEQ 2048
#define BATCH 4
#define HEADS 8
#define HDIM 160
#define MTOT (BATCH*SEQ)          // 8192
#define NQKV (3*D_MODEL)          // 3840

__device__ __forceinline__ void gload_lds16(const f16* g, f16* l) {
  __builtin_amdgcn_global_load_lds(
      (const __attribute__((address_space(1))) unsigned int*)g,
      (__attribute__((address_space(3))) unsigned int*)l,
      16, 0, 0);
}

#define BARX() { asm volatile("" ::: "memory"); __builtin_amdgcn_s_barrier(); asm volatile("" ::: "memory"); }
#define VMW(N) { asm volatile("s_waitcnt vmcnt(" #N ")" ::: "memory"); }

// ---------------- prep: x->f16 convert + 4x W_eff build, one launch ----------------
// blocks [0, 10240): convert; [10240, 16640): weff (1600 blocks per weight set).
__global__ void prep(const float* __restrict__ x, f16* __restrict__ xh,
                     const float* __restrict__ W0, const float* __restrict__ W1,
                     const float* __restrict__ W2, const float* __restrict__ W3,
                     const float* __restrict__ u0, const float* __restrict__ u1,
                     const float* __restrict__ u2, const float* __restrict__ u3,
                     const float* __restrict__ n0, const float* __restrict__ n1,
                     const float* __restrict__ n2, const float* __restrict__ n3,
                     f16* __restrict__ o0, f16* __restrict__ o1,
                     f16* __restrict__ o2, f16* __restrict__ o3) {
  int bid = blockIdx.x;
  if (bid < 10240) {
    int i = bid * 256 + threadIdx.x;           // MTOT*D_MODEL/4 elements
    float4 v = ((const float4*)x)[i];
    f16x4 o = { (f16)v.x, (f16)v.y, (f16)v.z, (f16)v.w };
    ((f16x4*)xh)[i] = o;
    return;
  }
  int w = bid - 10240;
  int which = w / 1600;
  const float* W    = which==0 ? W0 : which==1 ? W1 : which==2 ? W2 : W3;
  const float* up   = which==0 ? u0 : which==1 ? u1 : which==2 ? u2 : u3;
  const float* down = which==0 ? n0 : which==1 ? n1 : which==2 ? n2 : n3;
  f16* out          = which==0 ? o0 : which==1 ? o1 : which==2 ? o2 : o3;
  int idx = (w % 1600) * 256 + threadIdx.x;    // D*D/4 threads
  int o  = idx / (D_MODEL / 4);
  int i0 = (idx % (D_MODEL / 4)) * 4;
  float4 wv = *(const float4*)&W[(size_t)o * D_MODEL + i0];
  float p0 = up[o*4+0], p1 = up[o*4+1], p2 = up[o*4+2], p3 = up[o*4+3];
  float vals[4] = { wv.x, wv.y, wv.z, wv.w };
  f16x4 r;
#pragma unroll
  for (int j = 0; j < 4; ++j) {
    int i = i0 + j;
    float acc = vals[j] + p0*down[i] + p1*down[D_MODEL + i]
                        + p2*down[2*D_MODEL + i] + p3*down[3*D_MODEL + i];
    r[j] = (f16)acc;
  }
  *(f16x4*)&out[(size_t)o * D_MODEL + i0] = r;
}

// ---------------- 256x256 deep-pipelined GEMM ----------------
// C[M][N] = A[M][K] * Bw[N][K]^T; K=1280.
// OUTMODE 1: float out + bias (O-proj).
// OUTMODE 2: QKV — bn<10 writes f16 C (Q,K cols); bn>=10 writes V cols directly
//            into Vt [32 bh][160 d][2048 s] sigma-permuted (transpose fused);
//            V region of qkv is never written.
// XCD-aware bijective swizzle: xcd = flat&7 owns bm in [xcd*4, xcd*4+4).
template<int OUTMODE>
__global__ __launch_bounds__(512) void gemm256(const f16* __restrict__ A,
                                               const f16* __restrict__ Bw,
                                               void* __restrict__ Cp, int ldc,
                                               const float* __restrict__ bias,
                                               f16* __restrict__ Vt) {
  const int K = D_MODEL, NT = D_MODEL/64;               // 20 K-tiles
  __shared__ alignas(16) f16 lds[7 * 8192];             // A: slots 0..2, B: slots 3..6
  f16* LB = lds + 3*8192;
  int tid = threadIdx.x;
  int wv = tid >> 6, l = tid & 63;
  int wm = wv >> 2, wn = wv & 3;
  int lr = l & 15, lg = l >> 4;

  int flat = blockIdx.y * gridDim.x + blockIdx.x;
  int bnn = gridDim.x;
  int xcd = flat & 7, idx = flat >> 3;
  int bm = xcd * 4 + idx / bnn;
  int bn = idx % bnn;

  int row0 = tid >> 3;
  int csw  = ((tid & 7) ^ (row0 & 7)) * 8;
  const f16* Asrc[2]; const f16* Bsrc[2];
#pragma unroll
  for (int h = 0; h < 2; ++h) {
    Asrc[h] = A  + (size_t)(bm*256 + h*128 + row0) * K + csw;
    Bsrc[h] = Bw + (size_t)(bn*256 + h*128 + row0) * K + csw;
  }
  int ldsoff = wv * 512;

  int xsl0 = ((lg)     ^ (lr & 7)) * 8;
  int xsl1 = ((4 + lg) ^ (lr & 7)) * 8;

  f32x4 acc[8][4] = {};

#define STAGE_A(h, slot, kt) { const f16* s_ = Asrc[h] + (kt)*64; f16* d_ = lds + (slot)*8192 + ldsoff; \
    gload_lds16(s_, d_); gload_lds16(s_ + (size_t)64*K, d_ + 4096); }
#define STAGE_B(h, slot, kt) { const f16* s_ = Bsrc[h] + (kt)*64; f16* d_ = LB + (slot)*8192 + ldsoff; \
    gload_lds16(s_, d_); gload_lds16(s_ + (size_t)64*K, d_ + 4096); }

  STAGE_A(0, 0, 0); STAGE_A(1, 1, 0);
  STAGE_B(0, 0, 0); STAGE_B(1, 1, 0);
  STAGE_B(0, 2, 1);
  VMW(2); BARX();

  for (int t = 0; t < NT; ++t) {
    int sA0 = (2*t) % 3, sA1 = (2*t+1) % 3, sA2 = (2*t+2) % 3;
    int sB0 = (2*t) & 3, sB1 = (2*t+1) & 3, sB3 = (2*t+3) & 3;
    int tc1 = (t+1 < NT) ? t+1 : NT-1;
    int tc2 = (t+2 < NT) ? t+2 : NT-1;

#define PHASE(ah, bh, sA, sB, STG, VMOPT) { \
    f16x8 af[4][2], bf[2][2]; \
    _Pragma("unroll") \
    for (int j = 0; j < 4; ++j) { \
      int base = (sA)*8192 + (wm*64 + j*16 + lr)*64; \
      af[j][0] = *(const f16x8*)&lds[base + xsl0]; \
      af[j][1] = *(const f16x8*)&lds[base + xsl1]; \
    } \
    _Pragma("unroll") \
    for (int i = 0; i < 2; ++i) { \
      int base = (sB)*8192 + (wn*32 + i*16 + lr)*64; \
      bf[i][0] = *(const f16x8*)&LB[base + xsl0]; \
      bf[i][1] = *(const f16x8*)&LB[base + xsl1]; \
    } \
    STG; \
    BARX(); \
    __builtin_amdgcn_s_setprio(1); \
    _Pragma("unroll") \
    for (int j = 0; j < 4; ++j) \
      _Pragma("unroll") \
      for (int i = 0; i < 2; ++i) { \
        acc[(ah)*4+j][(bh)*2+i] = __builtin_amdgcn_mfma_f32_16x16x32_f16(af[j][0], bf[i][0], acc[(ah)*4+j][(bh)*2+i], 0, 0, 0); \
        acc[(ah)*4+j][(bh)*2+i] = __builtin_amdgcn_mfma_f32_16x16x32_f16(af[j][1], bf[i][1], acc[(ah)*4+j][(bh)*2+i], 0, 0, 0); \
      } \
    __builtin_amdgcn_s_setprio(0); \
    VMOPT; \
    BARX(); }

    PHASE(0, 0, sA0, sB0, STAGE_B(1, sB3, tc1), VMW(2))
    PHASE(1, 0, sA1, sB0, STAGE_A(0, sA2, tc1), )
    PHASE(0, 1, sA0, sB1, STAGE_B(0, sB0, tc2), )
    PHASE(1, 1, sA1, sB1, STAGE_A(1, sA0, tc1), VMW(4))
#undef PHASE
  }

  if (OUTMODE == 2 && bn >= 10) {
    // V columns: write sigma-permuted transpose directly into Vt.
    // Lane's 4 rows are 4 consecutive tokens within one 4-aligned sigma block.
#pragma unroll
    for (int nf = 0; nf < 4; ++nf) {
      int c  = bn*256 + (nf>>1)*128 + wn*32 + (nf&1)*16 + lr;
      int cv = c - 2*D_MODEL;
      int hh = cv / HDIM, d = cv % HDIM;
#pragma unroll
      for (int mf = 0; mf < 8; ++mf) {
        int r0 = bm*256 + (mf>>2)*128 + wm*64 + (mf&3)*16 + lg*4;
        int b = r0 >> 11, s0 = r0 & (SEQ-1);
        int soff = s0 & 31, sblk = s0 & ~31;
        int sj = (((soff>>2) ^ (soff>>3)) & 1) ? (soff ^ 12) : soff;
        f16x4 v = { (f16)acc[mf][nf][0], (f16)acc[mf][nf][1],
                    (f16)acc[mf][nf][2], (f16)acc[mf][nf][3] };
        *(f16x4*)&Vt[(size_t)((b*HEADS + hh)*HDIM + d) * SEQ + sblk + sj] = v;
      }
    }
  } else {
#pragma unroll
    for (int mf = 0; mf < 8; ++mf) {
      int r0 = bm*256 + (mf>>2)*128 + wm*64 + (mf&3)*16 + lg*4;
#pragma unroll
      for (int nf = 0; nf < 4; ++nf) {
        int c = bn*256 + (nf>>1)*128 + wn*32 + (nf&1)*16 + lr;
        if constexpr (OUTMODE == 1) {
          float bb = bias[c];
#pragma unroll
          for (int rg = 0; rg < 4; ++rg)
            ((float*)Cp)[(size_t)(r0 + rg) * ldc + c] = acc[mf][nf][rg] + bb;
        } else {
#pragma unroll
          for (int rg = 0; rg < 4; ++rg)
            ((f16*)Cp)[(size_t)(r0 + rg) * ldc + c] = (f16)acc[mf][nf][rg];
        }
      }
    }
  }
#undef STAGE_A
#undef STAGE_B
}

// ---------------- flash attention v5b ----------------
// R10 v5 structure + chain shaves (R12): tree smax, deferred lsum reduce.
__global__ __launch_bounds__(256, 2) void attn(const f16* __restrict__ qkv,
                                               const f16* __restrict__ Vt,
                                               f16* __restrict__ ctx) {
  __shared__ alignas(16) f16 Kl[64 * 168];    // 21504 B
  __shared__ alignas(16) f16 Vl[160 * 64];    // 20480 B
  int tid = threadIdx.x;
  int wv = tid >> 6, l = tid & 63;
  int lr = l & 15, lg = l >> 4;
  int flat = blockIdx.y * 16 + blockIdx.x;    // 512 blocks
  int xcd = flat & 7, idx = flat >> 3;        // idx 0..63
  int bh = xcd * 4 + (idx >> 4);              // 4 bh per XCD
  int qt = idx & 15;
  int b = bh >> 3, h = bh & 7;
  size_t qrow[2];
#pragma unroll
  for (int qg = 0; qg < 2; ++qg)
    qrow[qg] = (size_t)(b*SEQ + qt*128 + wv*32 + qg*16 + lr);

  // Q fragments, pre-scaled by hd^-0.5 * log2(e) (exp2 domain)
  const f16 qscale = (f16)0.114055069f;
  f16x8 qf[2][5];
#pragma unroll
  for (int qg = 0; qg < 2; ++qg)
#pragma unroll
    for (int dk = 0; dk < 5; ++dk) {
      f16x8 t = *(const f16x8*)&qkv[qrow[qg] * NQKV + h*HDIM + dk*32 + lg*8];
#pragma unroll
      for (int j = 0; j < 8; ++j) t[j] = t[j] * qscale;
      qf[qg][dk] = t;
    }

  // K staging: 1344 chunks (5x256 + 64 on wave 0); slot 20 = pad (garbage ok).
  const char* Kg0 = (const char*)qkv + (size_t)(b*SEQ)*NQKV*2 + (size_t)D_MODEL*2 + (size_t)h*HDIM*2;
  char* KlB = (char*)Kl;
  uint32_t koff[6];
  f16* kld[6];
#pragma unroll
  for (int it = 0; it < 6; ++it) {
    int p = (it < 5) ? it*256 + tid : 1280 + (tid & 63);
    koff[it] = (uint32_t)(p/21) * (NQKV*2) + (uint32_t)(p%21) * 16;
    kld[it] = (f16*)(KlB + ((it < 5) ? (it*256 + wv*64)*16 : 1280*16));
  }

  // V staging: 1280 chunks; content XOR-swizzled (phys slot sp holds logical sp^(row&7)).
  const char* Vg0 = (const char*)Vt + (size_t)bh*HDIM*SEQ*2;
  char* VlB = (char*)Vl;
  uint32_t voff[5];
  f16* vld[5];
#pragma unroll
  for (int it = 0; it < 5; ++it) {
    int c = it*256 + tid;
    int row = c >> 3, sp = c & 7;
    voff[it] = (uint32_t)row * (SEQ*2) + (uint32_t)((sp ^ (row & 7)) * 16);
    vld[it] = (f16*)(VlB + (it*256 + wv*64)*16);
  }
  uint32_t vro[2];
#pragma unroll
  for (int ks = 0; ks < 2; ++ks)
    vro[ks] = (uint32_t)lr*128 + (uint32_t)((((ks*4+lg) ^ (lr & 7)) * 16));

  f32x4 oacc[10][2] = {};
  float m[2] = {-1e30f, -1e30f}, lsum[2] = {0.f, 0.f};

  for (int kt = 0; kt < 32; ++kt) {
    const char* Ksrc = Kg0 + (size_t)kt * (64*NQKV*2);
    const char* Vsrc = Vg0 + (size_t)kt * 128;
#pragma unroll
    for (int it = 0; it < 5; ++it) {
      gload_lds16((const f16*)(Ksrc + koff[it]), kld[it]);
      gload_lds16((const f16*)(Vsrc + voff[it]), vld[it]);
    }
    if (wv == 0)
      gload_lds16((const f16*)(Ksrc + koff[5]), kld[5]);
    __syncthreads();

    // S^T[kr][q], both q-groups share each K fragment
    f32x4 sc[4][2] = {};
    __builtin_amdgcn_s_setprio(1);
#pragma unroll
    for (int kb = 0; kb < 4; ++kb)
#pragma unroll
      for (int dk = 0; dk < 5; ++dk) {
        f16x8 a = *(const f16x8*)&Kl[(kb*16 + lr)*168 + dk*32 + lg*8];
        sc[kb][0] = __builtin_amdgcn_mfma_f32_16x16x32_f16(a, qf[0][dk], sc[kb][0], 0, 0, 0);
        sc[kb][1] = __builtin_amdgcn_mfma_f32_16x16x32_f16(a, qf[1][dk], sc[kb][1], 0, 0, 0);
      }
    __builtin_amdgcn_s_setprio(0);

    // row maxes via pairwise tree (depth 4), then cross-lane reduce
    float smax[2];
#pragma unroll
    for (int qg = 0; qg < 2; ++qg) {
      float a0 = fmaxf(fmaxf(sc[0][qg][0], sc[0][qg][1]), fmaxf(sc[0][qg][2], sc[0][qg][3]));
      float a1 = fmaxf(fmaxf(sc[1][qg][0], sc[1][qg][1]), fmaxf(sc[1][qg][2], sc[1][qg][3]));
      float a2 = fmaxf(fmaxf(sc[2][qg][0], sc[2][qg][1]), fmaxf(sc[2][qg][2], sc[2][qg][3]));
      float a3 = fmaxf(fmaxf(sc[3][qg][0], sc[3][qg][1]), fmaxf(sc[3][qg][2], sc[3][qg][3]));
      float sm = fmaxf(fmaxf(a0, a1), fmaxf(a2, a3));
      sm = fmaxf(sm, __shfl_xor(sm, 16));
      sm = fmaxf(sm, __shfl_xor(sm, 32));
      smax[qg] = sm;
    }
    if (!__all(fmaxf(smax[0] - m[0], smax[1] - m[1]) <= 11.54f)) {
#pragma unroll
      for (int qg = 0; qg < 2; ++qg) {
        float mn = fmaxf(m[qg], smax[qg]);
        float alpha = exp2f(m[qg] - mn);
#pragma unroll
        for (int df = 0; df < 10; ++df)
#pragma unroll
          for (int rg = 0; rg < 4; ++rg) oacc[df][qg][rg] *= alpha;
        lsum[qg] *= alpha;
        m[qg] = mn;
      }
    }

    // per-qg: exp2 -> per-lane partial sum -> in-register repack
    f16x8 pb[2][2];
#pragma unroll
    for (int qg = 0; qg < 2; ++qg) {
      float ps[16];
#pragma unroll
      for (int kb = 0; kb < 4; ++kb)
#pragma unroll
        for (int rg = 0; rg < 4; ++rg)
          ps[kb*4 + rg] = exp2f(sc[kb][qg][rg] - m[qg]);
      float s0 = (ps[0] + ps[1]) + (ps[2] + ps[3]);
      float s1 = (ps[4] + ps[5]) + (ps[6] + ps[7]);
      float s2 = (ps[8] + ps[9]) + (ps[10] + ps[11]);
      float s3 = (ps[12] + ps[13]) + (ps[14] + ps[15]);
      lsum[qg] += (s0 + s1) + (s2 + s3);   // cross-lane reduce deferred

      uint32_t w0, w1, w2, w3, w4, w5, w6, w7;
      asm("v_cvt_pkrtz_f16_f32 %0, %1, %2" : "=v"(w0) : "v"(ps[0]),  "v"(ps[1]));
      asm("v_cvt_pkrtz_f16_f32 %0, %1, %2" : "=v"(w1) : "v"(ps[2]),  "v"(ps[3]));
      asm("v_cvt_pkrtz_f16_f32 %0, %1, %2" : "=v"(w2) : "v"(ps[4]),  "v"(ps[5]));
      asm("v_cvt_pkrtz_f16_f32 %0, %1, %2" : "=v"(w3) : "v"(ps[6]),  "v"(ps[7]));
      asm("v_cvt_pkrtz_f16_f32 %0, %1, %2" : "=v"(w4) : "v"(ps[8]),  "v"(ps[9]));
      asm("v_cvt_pkrtz_f16_f32 %0, %1, %2" : "=v"(w5) : "v"(ps[10]), "v"(ps[11]));
      asm("v_cvt_pkrtz_f16_f32 %0, %1, %2" : "=v"(w6) : "v"(ps[12]), "v"(ps[13]));
      asm("v_cvt_pkrtz_f16_f32 %0, %1, %2" : "=v"(w7) : "v"(ps[14]), "v"(ps[15]));
      asm("v_permlane32_swap_b32 %0, %1" : "+v"(w0), "+v"(w2));
      asm("v_permlane32_swap_b32 %0, %1" : "+v"(w1), "+v"(w3));
      asm("v_permlane32_swap_b32 %0, %1" : "+v"(w4), "+v"(w6));
      asm("v_permlane32_swap_b32 %0, %1" : "+v"(w5), "+v"(w7));
      u32x4 c0 = { w0, w1, w2, w3 };
      u32x4 c1 = { w4, w5, w6, w7 };
      pb[qg][0] = __builtin_bit_cast(f16x8, c0);
      pb[qg][1] = __builtin_bit_cast(f16x8, c1);
    }

    // PV: each V fragment feeds both q-groups
    __builtin_amdgcn_s_setprio(1);
#pragma unroll
    for (int df = 0; df < 10; ++df)
#pragma unroll
      for (int ks = 0; ks < 2; ++ks) {
        f16x8 a = *(const f16x8*)(VlB + vro[ks] + df*2048);
        oacc[df][0] = __builtin_amdgcn_mfma_f32_16x16x32_f16(a, pb[0][ks], oacc[df][0], 0, 0, 0);
        oacc[df][1] = __builtin_amdgcn_mfma_f32_16x16x32_f16(a, pb[1][ks], oacc[df][1], 0, 0, 0);
      }
    __builtin_amdgcn_s_setprio(0);
    __syncthreads();
  }

  // deferred cross-lane lsum reduction (partials consistently scaled by alpha)
#pragma unroll
  for (int qg = 0; qg < 2; ++qg) {
    lsum[qg] += __shfl_xor(lsum[qg], 16);
    lsum[qg] += __shfl_xor(lsum[qg], 32);
  }

#pragma unroll
  for (int qg = 0; qg < 2; ++qg) {
    float inv = 1.f / lsum[qg];
#pragma unroll
    for (int df = 0; df < 10; ++df)
#pragma unroll
      for (int pr = 0; pr < 2; ++pr) {
        f16x2 pv = { (f16)(oacc[df][qg][pr*2+0] * inv), (f16)(oacc[df][qg][pr*2+1] * inv) };
        *(f16x2*)&ctx[qrow[qg] * D_MODEL + h*HDIM + df*16 + lg*4 + pr*2] = pv;
      }
  }
}

// ---------------- launcher ----------------

extern "C" void kernel_launch(void* const* d_in, const int* in_sizes, int n_in,
                              void* d_out, int out_size, void* d_ws, size_t ws_size,
                              hipStream_t stream) {
  const float* x   = (const float*)d_in[0];
  const float* Wq  = (const float*)d_in[1];
  const float* Wk  = (const float*)d_in[2];
  const float* Wv  = (const float*)d_in[3];
  const float* Wo  = (const float*)d_in[4];
  const float* bo  = (const float*)d_in[5];
  const float* q_down = (const float*)d_in[6];
  const float* q_up   = (const float*)d_in[7];
  const float* k_down = (const float*)d_in[8];
  const float* k_up   = (const float*)d_in[9];
  const float* v_down = (const float*)d_in[10];
  const float* v_up   = (const float*)d_in[11];
  const float* o_down = (const float*)d_in[12];
  const float* o_up   = (const float*)d_in[13];
  float* out = (float*)d_out;

  char* ws = (char*)d_ws;
  f16* xh    = (f16*)ws;                                  // 8192x1280 (reused as ctx)
  f16* Wqkv  = (f16*)(ws + 20971520);                     // 3840x1280
  f16* WoE   = (f16*)(ws + 20971520 + 9830400);           // 1280x1280
  f16* qkv   = (f16*)(ws + 20971520 + 9830400 + 3276800); // 8192x3840 (V third unused)
  f16* Vt    = (f16*)(ws + 20971520 + 9830400 + 3276800 + 62914560); // 32x160x2048
  f16* ctx   = xh;

  prep<<<16640, 256, 0, stream>>>(x, xh,
      Wq, Wk, Wv, Wo, q_up, k_up, v_up, o_up, q_down, k_down, v_down, o_down,
      Wqkv, Wqkv + (size_t)D_MODEL*D_MODEL, Wqkv + (size_t)2*D_MODEL*D_MODEL, WoE);

  gemm256<2><<<dim3(NQKV/256, MTOT/256), 512, 0, stream>>>(xh, Wqkv, qkv, NQKV, nullptr, Vt);
  attn<<<dim3(SEQ/128, BATCH*HEADS), 256, 0, stream>>>(qkv, Vt, ctx);
  gemm256<1><<<dim3(D_MODEL/256, MTOT/256), 512, 0, stream>>>(ctx, WoE, out, D_MODEL, bo, nullptr);
  (void)in_sizes; (void)n_in; (void)out_size; (void)ws_size;
}